// Round 7
// baseline (2309.129 us; speedup 1.0000x reference)
//
#include <hip/hip_runtime.h>

#define NATOMS 100000
#define NPAIRS 3200000
// F_ATOM=75, F_PAIR=14, H=50, F_OUT=50

__device__ __forceinline__ unsigned short f2bf(float f) {
    unsigned int u = __float_as_uint(f);
    unsigned int r = (u + 0x7fffu + ((u >> 16) & 1u)) >> 16;   // RNE
    return (unsigned short)r;
}
__device__ __forceinline__ float bflo(unsigned int u) { return __uint_as_float(u << 16); }
__device__ __forceinline__ float bfhi(unsigned int u) { return __uint_as_float(u & 0xffff0000u); }
__device__ __forceinline__ unsigned int pack2(float a, float b) {
    return (unsigned int)f2bf(a) | ((unsigned int)f2bf(b) << 16);
}

// XA row layout (uints, stride 56 per atom = 224 B, 16B aligned):
//   uints 0..24  : X1' = af@W_AP[:, :75].T + b_AP   (pair-packed bf16)
//   uints 28..52 : X2  = af@W_AP[:, 75:].T
// (uints 25..27, 53..55 pad)

// K1: per-atom precompute. blockIdx.y = half so weight rows stay wave-uniform.
// waves_per_eu(2,2): pin allocator at the 256-VGPR tier (live ~95) - no spill.
__global__ __launch_bounds__(256) __attribute__((amdgpu_waves_per_eu(2, 2)))
void k_atom_pre(
    const float* __restrict__ af,
    const float* __restrict__ W_AA, const float* __restrict__ b_AA,
    const float* __restrict__ W_AP, const float* __restrict__ b_AP,
    float* __restrict__ AA, unsigned int* __restrict__ XAu)
{
    const int a = blockIdx.x * 256 + threadIdx.x;
    if (a >= NATOMS) return;
    const int half = blockIdx.y;

    const float* ar = af + (size_t)a * 75;
    float x[75];
#pragma unroll
    for (int k = 0; k < 75; ++k) x[k] = ar[k];

    const int jbase = half ? 26 : 0;
    const int jend  = half ? 50 : 26;

    float* aout = AA + (size_t)a * 50;
#pragma unroll 2
    for (int j = jbase; j < jend; ++j) {
        const float* wr = W_AA + (size_t)j * 75;
        float acc = b_AA[j];
#pragma unroll
        for (int k = 0; k < 75; ++k) acc = fmaf(x[k], wr[k], acc);
        aout[j] = fmaxf(acc, 0.0f);
    }

    unsigned int* xout = XAu + (size_t)a * 56;
    const int nu    = half ? 12 : 13;
    const int ubase = half ? 13 : 0;
#pragma unroll 1
    for (int u = 0; u < nu; ++u) {
        const int j = jbase + 2 * u;
        const float2* w0 = (const float2*)(W_AP + (size_t)j * 150);
        const float2* w1 = (const float2*)(W_AP + (size_t)(j + 1) * 150);
        float a0 = b_AP[j], a1 = b_AP[j + 1];
        float c0 = 0.0f,   c1 = 0.0f;
#pragma unroll
        for (int q = 0; q < 37; ++q) {
            float2 wa = w0[q], wb = w1[q];
            a0 = fmaf(x[2 * q], wa.x, a0); a0 = fmaf(x[2 * q + 1], wa.y, a0);
            a1 = fmaf(x[2 * q], wb.x, a1); a1 = fmaf(x[2 * q + 1], wb.y, a1);
        }
        a0 = fmaf(x[74], ((const float*)w0)[74], a0);
        a1 = fmaf(x[74], ((const float*)w1)[74], a1);
        c0 = fmaf(x[0], ((const float*)w0)[75], c0);
        c1 = fmaf(x[0], ((const float*)w1)[75], c1);
#pragma unroll
        for (int q = 0; q < 37; ++q) {
            float2 wa = ((const float2*)(((const float*)w0) + 76))[q];
            float2 wb = ((const float2*)(((const float*)w1) + 76))[q];
            c0 = fmaf(x[2 * q + 1], wa.x, c0); c0 = fmaf(x[2 * q + 2], wa.y, c0);
            c1 = fmaf(x[2 * q + 1], wb.x, c1); c1 = fmaf(x[2 * q + 2], wb.y, c1);
        }
        xout[ubase + u]      = pack2(a0, a1);
        xout[28 + ubase + u] = pack2(c0, c1);
    }
}

// K2: per-pair fused kernel, one thread per pair, 256 pairs/block.
// waves_per_eu(4,4): pin allocator at the 128-VGPR / 4-waves-per-EU tier.
// Rounds 3-6 proved the backend otherwise down-tiers (80/64/32 regs) and
// spills the ~80-reg live set to scratch. Phase B (pp) runs before Phase A
// (gather) so x[14] dies before the gather temps go live.
__global__ __launch_bounds__(256) __attribute__((amdgpu_waves_per_eu(4, 4)))
void k_pair(
    const float* __restrict__ pf,
    const int* __restrict__ psplit,
    const int* __restrict__ a2p,
    const float* __restrict__ W_PA, const float* __restrict__ b_PA,
    const float* __restrict__ W_PP, const float* __restrict__ b_PP,
    const float* __restrict__ W_P,  const float* __restrict__ b_P,
    const unsigned int* __restrict__ XAu,
    float* __restrict__ PAsum,
    float* __restrict__ Pout)
{
    __shared__ unsigned int pa_lds[256 * 27];  // stride 27 (odd)
    __shared__ int head_list[256];
    __shared__ int ps_lds[256];
    __shared__ int nheads;

    const int t = threadIdx.x;
    const int p = blockIdx.x * 256 + t;       // NPAIRS == 12500*256
    if (t == 0) nheads = 0;

    float x[14];
    {
        const float2* pr2 = (const float2*)(pf + (size_t)p * 14);
#pragma unroll
        for (int k = 0; k < 7; ++k) {
            float2 v = pr2[k];
            x[2 * k] = v.x; x[2 * k + 1] = v.y;
        }
    }
    ps_lds[t] = psplit[p];

    // PA = relu(pf@W_PA.T + b_PA) -> packed bf16 LDS, 2 rows/iter
#pragma unroll 1
    for (int u = 0; u < 25; ++u) {
        const int j = 2 * u;
        const float2* w0 = (const float2*)(W_PA + (size_t)j * 14);
        const float2* w1 = (const float2*)(W_PA + (size_t)(j + 1) * 14);
        float a0 = b_PA[j], a1 = b_PA[j + 1];
#pragma unroll
        for (int k = 0; k < 7; ++k) {
            float2 wa = w0[k], wb = w1[k];
            a0 = fmaf(x[2 * k], wa.x, a0); a0 = fmaf(x[2 * k + 1], wa.y, a0);
            a1 = fmaf(x[2 * k], wb.x, a1); a1 = fmaf(x[2 * k + 1], wb.y, a1);
        }
        pa_lds[t * 27 + u] = pack2(fmaxf(a0, 0.0f), fmaxf(a1, 0.0f));
    }

    // acc[50] = b_P; stream K through it.
    float acc[50];
#pragma unroll
    for (int o = 0; o < 50; ++o) acc[o] = b_P[o];

    // Phase B first: pp streamed two values at a time; x[14] dies here.
#pragma unroll 1
    for (int u = 0; u < 25; ++u) {
        const int j = 2 * u;
        const float2* w0 = (const float2*)(W_PP + (size_t)j * 14);
        const float2* w1 = (const float2*)(W_PP + (size_t)(j + 1) * 14);
        float a0 = b_PP[j], a1 = b_PP[j + 1];
#pragma unroll
        for (int k = 0; k < 7; ++k) {
            float2 wa = w0[k], wb = w1[k];
            a0 = fmaf(x[2 * k], wa.x, a0); a0 = fmaf(x[2 * k + 1], wa.y, a0);
            a1 = fmaf(x[2 * k], wb.x, a1); a1 = fmaf(x[2 * k + 1], wb.y, a1);
        }
        a0 = fmaxf(a0, 0.0f);
        a1 = fmaxf(a1, 0.0f);
#pragma unroll
        for (int o = 0; o < 50; ++o) {
            const float2 w = *(const float2*)(W_P + (size_t)o * 100 + 50 + j);  // 8B aligned
            acc[o] = fmaf(a0, w.x, acc[o]);
            acc[o] = fmaf(a1, w.y, acc[o]);
        }
    }

    // Phase A: gather chunks of 8 s-values, FMA into acc immediately.
    {
        const int2 ij = ((const int2*)a2p)[p];
        const uint4* xi4 = (const uint4*)(XAu + (size_t)ij.x * 56);
        const uint4* xj4 = (const uint4*)(XAu + (size_t)ij.y * 56);
#pragma unroll 1
        for (int c = 0; c < 6; ++c) {
            uint4 A = xi4[c];       // X1'_i elems 8c..8c+7
            uint4 B = xj4[7 + c];   // X2_j
            uint4 C = xj4[c];       // X1'_j
            uint4 D = xi4[7 + c];   // X2_i
            float s8[8];
            s8[0] = fmaxf(bflo(A.x) + bflo(B.x), 0.f) + fmaxf(bflo(C.x) + bflo(D.x), 0.f);
            s8[1] = fmaxf(bfhi(A.x) + bfhi(B.x), 0.f) + fmaxf(bfhi(C.x) + bfhi(D.x), 0.f);
            s8[2] = fmaxf(bflo(A.y) + bflo(B.y), 0.f) + fmaxf(bflo(C.y) + bflo(D.y), 0.f);
            s8[3] = fmaxf(bfhi(A.y) + bfhi(B.y), 0.f) + fmaxf(bfhi(C.y) + bfhi(D.y), 0.f);
            s8[4] = fmaxf(bflo(A.z) + bflo(B.z), 0.f) + fmaxf(bflo(C.z) + bflo(D.z), 0.f);
            s8[5] = fmaxf(bfhi(A.z) + bfhi(B.z), 0.f) + fmaxf(bfhi(C.z) + bfhi(D.z), 0.f);
            s8[6] = fmaxf(bflo(A.w) + bflo(B.w), 0.f) + fmaxf(bflo(C.w) + bflo(D.w), 0.f);
            s8[7] = fmaxf(bfhi(A.w) + bfhi(B.w), 0.f) + fmaxf(bfhi(C.w) + bfhi(D.w), 0.f);
#pragma unroll
            for (int o = 0; o < 50; ++o) {
                const float* wr = W_P + (size_t)o * 100 + 8 * c;
                acc[o] = fmaf(s8[0], wr[0], acc[o]);
                acc[o] = fmaf(s8[1], wr[1], acc[o]);
                acc[o] = fmaf(s8[2], wr[2], acc[o]);
                acc[o] = fmaf(s8[3], wr[3], acc[o]);
                acc[o] = fmaf(s8[4], wr[4], acc[o]);
                acc[o] = fmaf(s8[5], wr[5], acc[o]);
                acc[o] = fmaf(s8[6], wr[6], acc[o]);
                acc[o] = fmaf(s8[7], wr[7], acc[o]);
            }
        }
        // tail f=48,49
        const unsigned int* xiu = (const unsigned int*)xi4;
        const unsigned int* xju = (const unsigned int*)xj4;
        unsigned int A = xiu[24], B = xju[52], C = xju[24], D = xiu[52];
        float s48 = fmaxf(bflo(A) + bflo(B), 0.f) + fmaxf(bflo(C) + bflo(D), 0.f);
        float s49 = fmaxf(bfhi(A) + bfhi(B), 0.f) + fmaxf(bfhi(C) + bfhi(D), 0.f);
#pragma unroll
        for (int o = 0; o < 50; ++o) {
            const float* wr = W_P + (size_t)o * 100 + 48;
            acc[o] = fmaf(s48, wr[0], acc[o]);
            acc[o] = fmaf(s49, wr[1], acc[o]);
        }
    }

    // store P row (8B-aligned) as float2
    {
        float2* po2 = (float2*)(Pout + (size_t)p * 50);
#pragma unroll
        for (int q = 0; q < 25; ++q) {
            float2 v;
            v.x = fmaxf(acc[2 * q],     0.0f);
            v.y = fmaxf(acc[2 * q + 1], 0.0f);
            po2[q] = v;
        }
    }

    // segment-sum of PA (pair_split sorted): per-block run reduction + atomics
    __syncthreads();
    bool head = (t == 0) || (ps_lds[t] != ps_lds[t - 1]);
    if (head) {
        int idx = atomicAdd(&nheads, 1);
        head_list[idx] = t;
    }
    __syncthreads();

    const int nh = nheads;
    for (int w = t; w < nh * 25; w += 256) {
        const int r0  = head_list[w / 25];
        const int jc  = w % 25;
        const int seg = ps_lds[r0];
        float a0 = 0.0f, a1 = 0.0f;
        int rr = r0;
        do {
            unsigned int u = pa_lds[rr * 27 + jc];
            a0 += bflo(u);
            a1 += bfhi(u);
            ++rr;
        } while (rr < 256 && ps_lds[rr] == seg);
        atomicAdd(&PAsum[(size_t)seg * 50 + 2 * jc],     a0);
        atomicAdd(&PAsum[(size_t)seg * 50 + 2 * jc + 1], a1);
    }
}

// K3: A = relu(concat(AA, PAsum) @ W_A.T + b_A). blockIdx.y picks output half.
__global__ __launch_bounds__(256) __attribute__((amdgpu_waves_per_eu(2, 2)))
void k_atom_final(
    const float* __restrict__ AA, const float* __restrict__ PAsum,
    const float* __restrict__ W_A, const float* __restrict__ b_A,
    float* __restrict__ Aout)
{
    const int a = blockIdx.x * 256 + threadIdx.x;
    if (a >= NATOMS) return;
    const int o0 = blockIdx.y * 25;

    float v[100];
    {
        const float2* p1 = (const float2*)(AA + (size_t)a * 50);
        const float2* p2 = (const float2*)(PAsum + (size_t)a * 50);
#pragma unroll
        for (int q = 0; q < 25; ++q) {
            float2 u1 = p1[q], u2 = p2[q];
            v[2 * q] = u1.x;      v[2 * q + 1] = u1.y;
            v[50 + 2 * q] = u2.x; v[50 + 2 * q + 1] = u2.y;
        }
    }
    float* ao = Aout + (size_t)a * 50;
#pragma unroll 2
    for (int o = o0; o < o0 + 25; ++o) {
        const float4* w4 = (const float4*)(W_A + (size_t)o * 100);
        float acc = b_A[o];
#pragma unroll
        for (int q = 0; q < 25; ++q) {
            float4 w = w4[q];
            acc = fmaf(v[4 * q + 0], w.x, acc);
            acc = fmaf(v[4 * q + 1], w.y, acc);
            acc = fmaf(v[4 * q + 2], w.z, acc);
            acc = fmaf(v[4 * q + 3], w.w, acc);
        }
        ao[o] = fmaxf(acc, 0.0f);
    }
}

extern "C" void kernel_launch(void* const* d_in, const int* in_sizes, int n_in,
                              void* d_out, int out_size, void* d_ws, size_t ws_size,
                              hipStream_t stream)
{
    const float* atom_features = (const float*)d_in[0];
    const float* pair_features = (const float*)d_in[1];
    const int*   pair_split    = (const int*)d_in[2];
    const int*   atom_to_pair  = (const int*)d_in[3];
    const float* W_AA = (const float*)d_in[4];
    const float* b_AA = (const float*)d_in[5];
    const float* W_PA = (const float*)d_in[6];
    const float* b_PA = (const float*)d_in[7];
    const float* W_A  = (const float*)d_in[8];
    const float* b_A  = (const float*)d_in[9];
    const float* W_AP = (const float*)d_in[10];
    const float* b_AP = (const float*)d_in[11];
    const float* W_PP = (const float*)d_in[12];
    const float* b_PP = (const float*)d_in[13];
    const float* W_P  = (const float*)d_in[14];
    const float* b_P  = (const float*)d_in[15];

    float* out   = (float*)d_out;
    float* A_out = out;                              // [NATOMS,50]
    float* P_out = out + (size_t)NATOMS * 50;        // [NPAIRS,50]

    float*        AA    = (float*)d_ws;                               // 5,000,000 f32
    unsigned int* XAu   = (unsigned int*)(AA + (size_t)NATOMS * 50);  // 5,600,000 u32
    float*        PAsum = (float*)(XAu + (size_t)NATOMS * 56);        // 5,000,000 f32

    hipMemsetAsync(PAsum, 0, (size_t)NATOMS * 50 * sizeof(float), stream);

    k_atom_pre<<<dim3(391, 2), 256, 0, stream>>>(
        atom_features, W_AA, b_AA, W_AP, b_AP, AA, XAu);

    k_pair<<<NPAIRS / 256, 256, 0, stream>>>(
        pair_features, pair_split, atom_to_pair,
        W_PA, b_PA, W_PP, b_PP, W_P, b_P,
        XAu, PAsum, P_out);

    k_atom_final<<<dim3(391, 2), 256, 0, stream>>>(
        AA, PAsum, W_A, b_A, A_out);
}

// Round 8
// 1131.399 us; speedup vs baseline: 2.0410x; 2.0410x over previous
//
#include <hip/hip_runtime.h>

#define NATOMS 100000
#define NPAIRS 3200000
// F_ATOM=75, F_PAIR=14, H=50, F_OUT=50

using short8  = __attribute__((ext_vector_type(8))) short;
using float4v = __attribute__((ext_vector_type(4))) float;

__device__ __forceinline__ unsigned short f2bf(float f) {
    unsigned int u = __float_as_uint(f);
    unsigned int r = (u + 0x7fffu + ((u >> 16) & 1u)) >> 16;   // RNE
    return (unsigned short)r;
}
__device__ __forceinline__ float bflo(unsigned int u) { return __uint_as_float(u << 16); }
__device__ __forceinline__ float bfhi(unsigned int u) { return __uint_as_float(u & 0xffff0000u); }
__device__ __forceinline__ unsigned int pack2(float a, float b) {
    return (unsigned int)f2bf(a) | ((unsigned int)f2bf(b) << 16);
}
__device__ __forceinline__ float bf2f(unsigned short s) {
    return __uint_as_float((unsigned int)s << 16);
}

// ws layout:
//   AA    f32 [NATOMS*50]
//   XAu   u32 [NATOMS*56]   bf16-packed per-atom X1'(uints 0..24) / X2(28..52)
//   PAsum f32 [NATOMS*50]
//   WPb   u16 [64*128]      W_P  bf16, rows n (pad 50->64), cols k (pad 100->128)
//   WPPb  u16 [64*32]       W_PP bf16, pad 50->64 x 14->32
//   WPAb  u16 [64*32]       W_PA bf16

// K0: convert weights to padded bf16 tables (tiny)
__global__ __launch_bounds__(256) void k_wconv(
    const float* __restrict__ W_P, const float* __restrict__ W_PP,
    const float* __restrict__ W_PA,
    unsigned short* __restrict__ WPb, unsigned short* __restrict__ WPPb,
    unsigned short* __restrict__ WPAb)
{
    const int idx = blockIdx.x * 256 + threadIdx.x;
    if (idx < 64 * 128) {
        const int n = idx >> 7, k = idx & 127;
        WPb[idx] = (n < 50 && k < 100) ? f2bf(W_P[n * 100 + k]) : (unsigned short)0;
    }
    if (idx < 64 * 32) {
        const int n = idx >> 5, k = idx & 31;
        WPPb[idx] = (n < 50 && k < 14) ? f2bf(W_PP[n * 14 + k]) : (unsigned short)0;
        WPAb[idx] = (n < 50 && k < 14) ? f2bf(W_PA[n * 14 + k]) : (unsigned short)0;
    }
}

// K1: per-atom precompute (unchanged from round 7)
__global__ __launch_bounds__(256) __attribute__((amdgpu_waves_per_eu(2, 2)))
void k_atom_pre(
    const float* __restrict__ af,
    const float* __restrict__ W_AA, const float* __restrict__ b_AA,
    const float* __restrict__ W_AP, const float* __restrict__ b_AP,
    float* __restrict__ AA, unsigned int* __restrict__ XAu)
{
    const int a = blockIdx.x * 256 + threadIdx.x;
    if (a >= NATOMS) return;
    const int half = blockIdx.y;

    const float* ar = af + (size_t)a * 75;
    float x[75];
#pragma unroll
    for (int k = 0; k < 75; ++k) x[k] = ar[k];

    const int jbase = half ? 26 : 0;
    const int jend  = half ? 50 : 26;

    float* aout = AA + (size_t)a * 50;
#pragma unroll 2
    for (int j = jbase; j < jend; ++j) {
        const float* wr = W_AA + (size_t)j * 75;
        float acc = b_AA[j];
#pragma unroll
        for (int k = 0; k < 75; ++k) acc = fmaf(x[k], wr[k], acc);
        aout[j] = fmaxf(acc, 0.0f);
    }

    unsigned int* xout = XAu + (size_t)a * 56;
    const int nu    = half ? 12 : 13;
    const int ubase = half ? 13 : 0;
#pragma unroll 1
    for (int u = 0; u < nu; ++u) {
        const int j = jbase + 2 * u;
        const float2* w0 = (const float2*)(W_AP + (size_t)j * 150);
        const float2* w1 = (const float2*)(W_AP + (size_t)(j + 1) * 150);
        float a0 = b_AP[j], a1 = b_AP[j + 1];
        float c0 = 0.0f,   c1 = 0.0f;
#pragma unroll
        for (int q = 0; q < 37; ++q) {
            float2 wa = w0[q], wb = w1[q];
            a0 = fmaf(x[2 * q], wa.x, a0); a0 = fmaf(x[2 * q + 1], wa.y, a0);
            a1 = fmaf(x[2 * q], wb.x, a1); a1 = fmaf(x[2 * q + 1], wb.y, a1);
        }
        a0 = fmaf(x[74], ((const float*)w0)[74], a0);
        a1 = fmaf(x[74], ((const float*)w1)[74], a1);
        c0 = fmaf(x[0], ((const float*)w0)[75], c0);
        c1 = fmaf(x[0], ((const float*)w1)[75], c1);
#pragma unroll
        for (int q = 0; q < 37; ++q) {
            float2 wa = ((const float2*)(((const float*)w0) + 76))[q];
            float2 wb = ((const float2*)(((const float*)w1) + 76))[q];
            c0 = fmaf(x[2 * q + 1], wa.x, c0); c0 = fmaf(x[2 * q + 2], wa.y, c0);
            c1 = fmaf(x[2 * q + 1], wb.x, c1); c1 = fmaf(x[2 * q + 2], wb.y, c1);
        }
        xout[ubase + u]      = pack2(a0, a1);
        xout[28 + ubase + u] = pack2(c0, c1);
    }
}

// helper: one gather chunk of 8 s-values -> 4 packed uints
__device__ __forceinline__ void s_chunk(
    const uint4* xi4, const uint4* xj4, int c, unsigned int* srow)
{
    uint4 A = xi4[c], B = xj4[7 + c], C = xj4[c], D = xi4[7 + c];
    float e0 = fmaxf(bflo(A.x) + bflo(B.x), 0.f) + fmaxf(bflo(C.x) + bflo(D.x), 0.f);
    float e1 = fmaxf(bfhi(A.x) + bfhi(B.x), 0.f) + fmaxf(bfhi(C.x) + bfhi(D.x), 0.f);
    float e2 = fmaxf(bflo(A.y) + bflo(B.y), 0.f) + fmaxf(bflo(C.y) + bflo(D.y), 0.f);
    float e3 = fmaxf(bfhi(A.y) + bfhi(B.y), 0.f) + fmaxf(bfhi(C.y) + bfhi(D.y), 0.f);
    float e4 = fmaxf(bflo(A.z) + bflo(B.z), 0.f) + fmaxf(bflo(C.z) + bflo(D.z), 0.f);
    float e5 = fmaxf(bfhi(A.z) + bfhi(B.z), 0.f) + fmaxf(bfhi(C.z) + bfhi(D.z), 0.f);
    float e6 = fmaxf(bflo(A.w) + bflo(B.w), 0.f) + fmaxf(bflo(C.w) + bflo(D.w), 0.f);
    float e7 = fmaxf(bfhi(A.w) + bfhi(B.w), 0.f) + fmaxf(bfhi(C.w) + bfhi(D.w), 0.f);
    srow[4 * c + 0] = pack2(e0, e1);
    srow[4 * c + 1] = pack2(e2, e3);
    srow[4 * c + 2] = pack2(e4, e5);
    srow[4 * c + 3] = pack2(e6, e7);
}

// K2: per-pair fused kernel, MFMA for PP/PA/P GEMMs. 512 thr = 8 waves,
// 128 pairs/block, wave w owns M-tile [16w,16w+16). All producer->consumer
// flow is wave-local (in-order DS within a wave) -> single barrier before
// the cross-wave segment reduce. No thread holds any 50-wide f32 array, so
// the ~40-reg live set fits the allocator's 64-VGPR tier without spilling.
__global__ __launch_bounds__(512) void k_pair(
    const float* __restrict__ pf,
    const int* __restrict__ psplit,
    const int* __restrict__ a2p,
    const float* __restrict__ b_PA,
    const float* __restrict__ b_PP,
    const float* __restrict__ b_P,
    const unsigned short* __restrict__ WPb,
    const unsigned short* __restrict__ WPPb,
    const unsigned short* __restrict__ WPAb,
    const unsigned int* __restrict__ XAu,
    float* __restrict__ PAsum,
    float* __restrict__ Pout)
{
    // S: [128 pairs][136 bf16]: k 0..49 = s, 50..99 = pp, 100..127 = zero pad.
    // stride 136 (272B): 16B-aligned rows, 2-way bank alias only (free).
    __shared__ unsigned short S_lds[128 * 136];
    // U: per-M-tile union: first pf-staging [16][32] bf16, later PA [16][50] bf16.
    __shared__ unsigned short U_lds[8 * 800];
    __shared__ int ps_lds[128];
    __shared__ unsigned char head_list[128];
    __shared__ int nheads;

    const int t   = threadIdx.x;
    const int blk = blockIdx.x;
    const int pl  = t >> 2;        // pair-local 0..127
    const int sub = t & 3;
    const int p   = blk * 128 + pl;    // NPAIRS == 25000*128
    const int w   = t >> 6;        // wave 0..7
    const int l   = t & 63;
    const int lr  = l & 15;        // row/col-in-tile
    const int lk  = l >> 4;        // k-subgroup 0..3

    if (t == 0) nheads = 0;
    if (t < 128) ps_lds[t] = psplit[blk * 128 + t];

    // ---- stage pf -> Pf view of U tile (bf16 [r][32], zero-padded) ----
    {
        unsigned short* Pf_row = &U_lds[(pl >> 4) * 800 + (pl & 15) * 32];
        const float2* pr2 = (const float2*)(pf + (size_t)p * 14);
        float2 v = pr2[sub];
        Pf_row[2 * sub]     = f2bf(v.x);
        Pf_row[2 * sub + 1] = f2bf(v.y);
        if (sub < 3) {
            float2 v2 = pr2[4 + sub];
            Pf_row[2 * (4 + sub)]     = f2bf(v2.x);
            Pf_row[2 * (4 + sub) + 1] = f2bf(v2.y);
        }
#pragma unroll
        for (int i = 0; i < 5; ++i) {
            int k = 14 + sub + 4 * i;
            if (k < 32) Pf_row[k] = 0;
        }
    }

    // ---- gather s -> S_lds[pl][0..49], zero pads k=100..127 ----
    {
        const int2 ij = ((const int2*)a2p)[p];
        const uint4* xi4 = (const uint4*)(XAu + (size_t)ij.x * 56);
        const uint4* xj4 = (const uint4*)(XAu + (size_t)ij.y * 56);
        unsigned int* srow = (unsigned int*)&S_lds[pl * 136];   // 272B rows: 4B ok
        s_chunk(xi4, xj4, sub, srow);
        if (sub < 2) s_chunk(xi4, xj4, 4 + sub, srow);
        if (sub == 2) {
            const unsigned int* xiu = (const unsigned int*)xi4;
            const unsigned int* xju = (const unsigned int*)xj4;
            unsigned int A = xiu[24], B = xju[52], C = xju[24], D = xiu[52];
            float s48 = fmaxf(bflo(A) + bflo(B), 0.f) + fmaxf(bflo(C) + bflo(D), 0.f);
            float s49 = fmaxf(bfhi(A) + bfhi(B), 0.f) + fmaxf(bfhi(C) + bfhi(D), 0.f);
            srow[24] = pack2(s48, s49);
        }
#pragma unroll
        for (int i = 0; i < 4; ++i) {
            int u = 50 + sub + 4 * i;      // uints 50..63 = bf16 k 100..127
            if (u < 64) srow[u] = 0;
        }
    }

    // ---- PP & PA GEMMs via MFMA: [16 pairs][32k] x [32k][64n], one k-step ----
    {
        short8 a = *(const short8*)&U_lds[w * 800 + lr * 32 + lk * 8];
        float4v accPP[4], accPA[4];
#pragma unroll
        for (int nt = 0; nt < 4; ++nt) {
            short8 bpp = *(const short8*)(WPPb + (nt * 16 + lr) * 32 + lk * 8);
            short8 bpa = *(const short8*)(WPAb + (nt * 16 + lr) * 32 + lk * 8);
            accPP[nt] = __builtin_amdgcn_mfma_f32_16x16x32_bf16(a, bpp, (float4v){0.f, 0.f, 0.f, 0.f}, 0, 0, 0);
            accPA[nt] = __builtin_amdgcn_mfma_f32_16x16x32_bf16(a, bpa, (float4v){0.f, 0.f, 0.f, 0.f}, 0, 0, 0);
        }
        // D layout: lane holds (row m = lk*4+j, col n = nt*16+lr)
#pragma unroll
        for (int nt = 0; nt < 4; ++nt) {
            const int n = nt * 16 + lr;
            if (n < 50) {
                const float bpp_ = b_PP[n];
                const float bpa_ = b_PA[n];
#pragma unroll
                for (int j = 0; j < 4; ++j) {
                    const int r = lk * 4 + j;
                    S_lds[(16 * w + r) * 136 + 50 + n] = f2bf(fmaxf(accPP[nt][j] + bpp_, 0.f));
                    U_lds[w * 800 + r * 50 + n]        = f2bf(fmaxf(accPA[nt][j] + bpa_, 0.f));  // PA view (Pf dead)
                }
            }
        }
    }

    // ---- P GEMM: [16 pairs][128k] x [128k][64n], 4 k-steps ----
    {
        float4v acc[4];
#pragma unroll
        for (int nt = 0; nt < 4; ++nt) acc[nt] = (float4v){0.f, 0.f, 0.f, 0.f};
#pragma unroll
        for (int ks = 0; ks < 4; ++ks) {
            short8 a = *(const short8*)&S_lds[(16 * w + lr) * 136 + ks * 32 + lk * 8];
#pragma unroll
            for (int nt = 0; nt < 4; ++nt) {
                short8 b = *(const short8*)(WPb + (nt * 16 + lr) * 128 + ks * 32 + lk * 8);
                acc[nt] = __builtin_amdgcn_mfma_f32_16x16x32_bf16(a, b, acc[nt], 0, 0, 0);
            }
        }
#pragma unroll
        for (int nt = 0; nt < 4; ++nt) {
            const int n = nt * 16 + lr;
            if (n < 50) {
                const float bias = b_P[n];
                const size_t base = ((size_t)blk * 128 + 16 * w) * 50 + n;
#pragma unroll
                for (int j = 0; j < 4; ++j) {
                    const int m = lk * 4 + j;
                    Pout[base + (size_t)m * 50] = fmaxf(acc[nt][j] + bias, 0.f);
                }
            }
        }
    }

    // ---- segment-sum of PA (cross-wave: one barrier) ----
    __syncthreads();
    if (t < 128) {
        bool head = (t == 0) || (ps_lds[t] != ps_lds[t - 1]);
        if (head) {
            int idx = atomicAdd(&nheads, 1);
            head_list[idx] = (unsigned char)t;
        }
    }
    __syncthreads();

    const int nh = nheads;
    for (int iw = t; iw < nh * 50; iw += 512) {
        const int r0  = head_list[iw / 50];
        const int f   = iw % 50;
        const int seg = ps_lds[r0];
        float a0 = 0.0f;
        int rr = r0;
        do {
            a0 += bf2f(U_lds[(rr >> 4) * 800 + (rr & 15) * 50 + f]);
            ++rr;
        } while (rr < 128 && ps_lds[rr] == seg);
        atomicAdd(&PAsum[(size_t)seg * 50 + f], a0);
    }
}

// K3: A = relu(concat(AA, PAsum) @ W_A.T + b_A) (unchanged from round 7)
__global__ __launch_bounds__(256) __attribute__((amdgpu_waves_per_eu(2, 2)))
void k_atom_final(
    const float* __restrict__ AA, const float* __restrict__ PAsum,
    const float* __restrict__ W_A, const float* __restrict__ b_A,
    float* __restrict__ Aout)
{
    const int a = blockIdx.x * 256 + threadIdx.x;
    if (a >= NATOMS) return;
    const int o0 = blockIdx.y * 25;

    float v[100];
    {
        const float2* p1 = (const float2*)(AA + (size_t)a * 50);
        const float2* p2 = (const float2*)(PAsum + (size_t)a * 50);
#pragma unroll
        for (int q = 0; q < 25; ++q) {
            float2 u1 = p1[q], u2 = p2[q];
            v[2 * q] = u1.x;      v[2 * q + 1] = u1.y;
            v[50 + 2 * q] = u2.x; v[50 + 2 * q + 1] = u2.y;
        }
    }
    float* ao = Aout + (size_t)a * 50;
#pragma unroll 2
    for (int o = o0; o < o0 + 25; ++o) {
        const float4* w4 = (const float4*)(W_A + (size_t)o * 100);
        float acc = b_A[o];
#pragma unroll
        for (int q = 0; q < 25; ++q) {
            float4 w = w4[q];
            acc = fmaf(v[4 * q + 0], w.x, acc);
            acc = fmaf(v[4 * q + 1], w.y, acc);
            acc = fmaf(v[4 * q + 2], w.z, acc);
            acc = fmaf(v[4 * q + 3], w.w, acc);
        }
        ao[o] = fmaxf(acc, 0.0f);
    }
}

extern "C" void kernel_launch(void* const* d_in, const int* in_sizes, int n_in,
                              void* d_out, int out_size, void* d_ws, size_t ws_size,
                              hipStream_t stream)
{
    const float* atom_features = (const float*)d_in[0];
    const float* pair_features = (const float*)d_in[1];
    const int*   pair_split    = (const int*)d_in[2];
    const int*   atom_to_pair  = (const int*)d_in[3];
    const float* W_AA = (const float*)d_in[4];
    const float* b_AA = (const float*)d_in[5];
    const float* W_PA = (const float*)d_in[6];
    const float* b_PA = (const float*)d_in[7];
    const float* W_A  = (const float*)d_in[8];
    const float* b_A  = (const float*)d_in[9];
    const float* W_AP = (const float*)d_in[10];
    const float* b_AP = (const float*)d_in[11];
    const float* W_PP = (const float*)d_in[12];
    const float* b_PP = (const float*)d_in[13];
    const float* W_P  = (const float*)d_in[14];
    const float* b_P  = (const float*)d_in[15];

    float* out   = (float*)d_out;
    float* A_out = out;                              // [NATOMS,50]
    float* P_out = out + (size_t)NATOMS * 50;        // [NPAIRS,50]

    float*          AA    = (float*)d_ws;                               // 5,000,000 f32
    unsigned int*   XAu   = (unsigned int*)(AA + (size_t)NATOMS * 50);  // 5,600,000 u32
    float*          PAsum = (float*)(XAu + (size_t)NATOMS * 56);        // 5,000,000 f32
    unsigned short* WPb   = (unsigned short*)(PAsum + (size_t)NATOMS * 50);  // 8192 u16
    unsigned short* WPPb  = WPb + 64 * 128;                                  // 2048 u16
    unsigned short* WPAb  = WPPb + 64 * 32;                                  // 2048 u16

    hipMemsetAsync(PAsum, 0, (size_t)NATOMS * 50 * sizeof(float), stream);

    k_wconv<<<32, 256, 0, stream>>>(W_P, W_PP, W_PA, WPb, WPPb, WPAb);

    k_atom_pre<<<dim3(391, 2), 256, 0, stream>>>(
        atom_features, W_AA, b_AA, W_AP, b_AP, AA, XAu);

    k_pair<<<NPAIRS / 128, 512, 0, stream>>>(
        pair_features, pair_split, atom_to_pair,
        b_PA, b_PP, b_P, WPb, WPPb, WPAb,
        XAu, PAsum, P_out);

    k_atom_final<<<dim3(391, 2), 256, 0, stream>>>(
        AA, PAsum, W_A, b_A, A_out);
}

// Round 9
// 1068.625 us; speedup vs baseline: 2.1608x; 1.0587x over previous
//
#include <hip/hip_runtime.h>

#define NATOMS 100000
#define NPAIRS 3200000
// F_ATOM=75, F_PAIR=14, H=50, F_OUT=50

using short8  = __attribute__((ext_vector_type(8))) short;
using float4v = __attribute__((ext_vector_type(4))) float;

__device__ __forceinline__ unsigned short f2bf(float f) {
    unsigned int u = __float_as_uint(f);
    unsigned int r = (u + 0x7fffu + ((u >> 16) & 1u)) >> 16;   // RNE
    return (unsigned short)r;
}
__device__ __forceinline__ float bflo(unsigned int u) { return __uint_as_float(u << 16); }
__device__ __forceinline__ float bfhi(unsigned int u) { return __uint_as_float(u & 0xffff0000u); }
__device__ __forceinline__ unsigned int pack2(float a, float b) {
    return (unsigned int)f2bf(a) | ((unsigned int)f2bf(b) << 16);
}
__device__ __forceinline__ float bf2f(unsigned short s) {
    return __uint_as_float((unsigned int)s << 16);
}

// ws: AA f32[NATOMS*50] | XAu u32[NATOMS*56] | PAsum f32[NATOMS*50]
//     WPb u16[64*128] (k<50: W_P s-part; k=50: b_P; 52<=k<102: W_P pp-part; else 0)
//     WPPb/WPAb u16[64*32] (k<14: W; k=14: bias; else 0)

// K0: weight tables (bias folded at the constant-1.0 k-slots)
__global__ __launch_bounds__(256) void k_wconv(
    const float* __restrict__ W_P,  const float* __restrict__ b_P,
    const float* __restrict__ W_PP, const float* __restrict__ b_PP,
    const float* __restrict__ W_PA, const float* __restrict__ b_PA,
    unsigned short* __restrict__ WPb, unsigned short* __restrict__ WPPb,
    unsigned short* __restrict__ WPAb)
{
    const int idx = blockIdx.x * 256 + threadIdx.x;
    if (idx < 64 * 128) {
        const int n = idx >> 7, k = idx & 127;
        float v = 0.0f;
        if (n < 50) {
            if (k < 50)                 v = W_P[n * 100 + k];
            else if (k == 50)           v = b_P[n];
            else if (k >= 52 && k < 102) v = W_P[n * 100 + 50 + (k - 52)];
        }
        WPb[idx] = f2bf(v);
    }
    if (idx < 64 * 32) {
        const int n = idx >> 5, k = idx & 31;
        float vp = 0.0f, va = 0.0f;
        if (n < 50) {
            if (k < 14)      { vp = W_PP[n * 14 + k]; va = W_PA[n * 14 + k]; }
            else if (k == 14){ vp = b_PP[n];          va = b_PA[n]; }
        }
        WPPb[idx] = f2bf(vp);
        WPAb[idx] = f2bf(va);
    }
}

// K1: per-atom precompute (unchanged — proven no-spill)
__global__ __launch_bounds__(256) __attribute__((amdgpu_waves_per_eu(2, 2)))
void k_atom_pre(
    const float* __restrict__ af,
    const float* __restrict__ W_AA, const float* __restrict__ b_AA,
    const float* __restrict__ W_AP, const float* __restrict__ b_AP,
    float* __restrict__ AA, unsigned int* __restrict__ XAu)
{
    const int a = blockIdx.x * 256 + threadIdx.x;
    if (a >= NATOMS) return;
    const int half = blockIdx.y;

    const float* ar = af + (size_t)a * 75;
    float x[75];
#pragma unroll
    for (int k = 0; k < 75; ++k) x[k] = ar[k];

    const int jbase = half ? 26 : 0;
    const int jend  = half ? 50 : 26;

    float* aout = AA + (size_t)a * 50;
#pragma unroll 2
    for (int j = jbase; j < jend; ++j) {
        const float* wr = W_AA + (size_t)j * 75;
        float acc = b_AA[j];
#pragma unroll
        for (int k = 0; k < 75; ++k) acc = fmaf(x[k], wr[k], acc);
        aout[j] = fmaxf(acc, 0.0f);
    }

    unsigned int* xout = XAu + (size_t)a * 56;
    const int nu    = half ? 12 : 13;
    const int ubase = half ? 13 : 0;
#pragma unroll 1
    for (int u = 0; u < nu; ++u) {
        const int j = jbase + 2 * u;
        const float2* w0 = (const float2*)(W_AP + (size_t)j * 150);
        const float2* w1 = (const float2*)(W_AP + (size_t)(j + 1) * 150);
        float a0 = b_AP[j], a1 = b_AP[j + 1];
        float c0 = 0.0f,   c1 = 0.0f;
#pragma unroll
        for (int q = 0; q < 37; ++q) {
            float2 wa = w0[q], wb = w1[q];
            a0 = fmaf(x[2 * q], wa.x, a0); a0 = fmaf(x[2 * q + 1], wa.y, a0);
            a1 = fmaf(x[2 * q], wb.x, a1); a1 = fmaf(x[2 * q + 1], wb.y, a1);
        }
        a0 = fmaf(x[74], ((const float*)w0)[74], a0);
        a1 = fmaf(x[74], ((const float*)w1)[74], a1);
        c0 = fmaf(x[0], ((const float*)w0)[75], c0);
        c1 = fmaf(x[0], ((const float*)w1)[75], c1);
#pragma unroll
        for (int q = 0; q < 37; ++q) {
            float2 wa = ((const float2*)(((const float*)w0) + 76))[q];
            float2 wb = ((const float2*)(((const float*)w1) + 76))[q];
            c0 = fmaf(x[2 * q + 1], wa.x, c0); c0 = fmaf(x[2 * q + 2], wa.y, c0);
            c1 = fmaf(x[2 * q + 1], wb.x, c1); c1 = fmaf(x[2 * q + 2], wb.y, c1);
        }
        xout[ubase + u]      = pack2(a0, a1);
        xout[28 + ubase + u] = pack2(c0, c1);
    }
}

// one gather chunk of 8 s-values -> 4 swizzled u32 stores
__device__ __forceinline__ void s_chunk(
    uint4 A, uint4 B, uint4 C, uint4 D, int c, unsigned int* srow, int swzd)
{
    float e0 = fmaxf(bflo(A.x) + bflo(B.x), 0.f) + fmaxf(bflo(C.x) + bflo(D.x), 0.f);
    float e1 = fmaxf(bfhi(A.x) + bfhi(B.x), 0.f) + fmaxf(bfhi(C.x) + bfhi(D.x), 0.f);
    float e2 = fmaxf(bflo(A.y) + bflo(B.y), 0.f) + fmaxf(bflo(C.y) + bflo(D.y), 0.f);
    float e3 = fmaxf(bfhi(A.y) + bfhi(B.y), 0.f) + fmaxf(bfhi(C.y) + bfhi(D.y), 0.f);
    float e4 = fmaxf(bflo(A.z) + bflo(B.z), 0.f) + fmaxf(bflo(C.z) + bflo(D.z), 0.f);
    float e5 = fmaxf(bfhi(A.z) + bfhi(B.z), 0.f) + fmaxf(bfhi(C.z) + bfhi(D.z), 0.f);
    float e6 = fmaxf(bflo(A.w) + bflo(B.w), 0.f) + fmaxf(bflo(C.w) + bflo(D.w), 0.f);
    float e7 = fmaxf(bfhi(A.w) + bfhi(B.w), 0.f) + fmaxf(bfhi(C.w) + bfhi(D.w), 0.f);
    srow[(4 * c + 0) ^ swzd] = pack2(e0, e1);
    srow[(4 * c + 1) ^ swzd] = pack2(e2, e3);
    srow[(4 * c + 2) ^ swzd] = pack2(e4, e5);
    srow[(4 * c + 3) ^ swzd] = pack2(e6, e7);
}

// K2: per-pair fused MFMA kernel. 512 thr = 8 waves, 128 pairs/block.
// All loads hoisted (a2p/pf first, gather right after a2p). MFMA operands
// swapped (A=W) so lanes hold consecutive-n outputs -> b64 LDS writes and
// float2 global stores. S rows XOR-swizzled ((row&7)<<4 on bytes).
__global__ __launch_bounds__(512) void k_pair(
    const float* __restrict__ pf,
    const int* __restrict__ psplit,
    const int* __restrict__ a2p,
    const unsigned short* __restrict__ WPb,
    const unsigned short* __restrict__ WPPb,
    const unsigned short* __restrict__ WPAb,
    const unsigned int* __restrict__ XAu,
    float* __restrict__ PAsum,
    float* __restrict__ Pout)
{
    // S: [128 pairs] x 68 u32 (136 u16): k0..49 = s, k50 = 1.0, k51 = 0,
    // k52..101 = pp, k102..127 = 0. Only first 64 u32 accessed; swizzle-safe.
    __shared__ unsigned int  S32[128 * 68];
    // U: [8 tiles][16 rows][56 u16]: first pf staging (k0..31), later PA (n0..49).
    __shared__ unsigned short U16[8 * 896];
    __shared__ int ps_lds[128];
    __shared__ unsigned char head_list[128];
    __shared__ int nheads;

    const int t   = threadIdx.x;
    const int blk = blockIdx.x;
    const int pl  = t >> 2;          // pair-local 0..127
    const int sub = t & 3;
    const int p   = blk * 128 + pl;  // NPAIRS == 25000*128
    const int w   = t >> 6;          // wave 0..7
    const int l   = t & 63;
    const int lr  = l & 15;
    const int lk  = l >> 4;

    if (t == 0) nheads = 0;
    if (t < 128) ps_lds[t] = psplit[blk * 128 + t];

    // ---- early independent loads ----
    const int2 ij = ((const int2*)a2p)[p];
    float2 pfa, pfb, pfc, pfd;
    {
        const float2* pr2 = (const float2*)(pf + (size_t)p * 14);
        if (sub == 0) { pfa = pr2[0]; pfb = pr2[1]; pfc = pr2[2]; pfd = pr2[3]; }
        else if (sub == 1) { pfa = pr2[4]; pfb = pr2[5]; pfc = pr2[6]; }
    }

    // ---- dependent gather (issued as soon as ij lands) ----
    const uint4* xi4 = (const uint4*)(XAu + (size_t)ij.x * 56);
    const uint4* xj4 = (const uint4*)(XAu + (size_t)ij.y * 56);
    uint4 A0 = xi4[sub], B0 = xj4[7 + sub], C0 = xj4[sub], D0 = xi4[7 + sub];
    uint4 A1, B1, C1, D1;
    unsigned int tA = 0, tB = 0, tC = 0, tD = 0;
    if (sub < 2) { A1 = xi4[4 + sub]; B1 = xj4[11 + sub]; C1 = xj4[4 + sub]; D1 = xi4[11 + sub]; }
    if (sub == 2) {
        const unsigned int* xiu = (const unsigned int*)xi4;
        const unsigned int* xju = (const unsigned int*)xj4;
        tA = xiu[24]; tB = xju[52]; tC = xju[24]; tD = xiu[52];
    }

    // ---- stage pf -> U (bf16 [row][k<32]; k14 = 1.0 bias slot; k>=14 zero) ----
    {
        uint4 q = {0u, 0u, 0u, 0u};
        if (sub == 0) {
            q.x = pack2(pfa.x, pfa.y); q.y = pack2(pfb.x, pfb.y);
            q.z = pack2(pfc.x, pfc.y); q.w = pack2(pfd.x, pfd.y);
        } else if (sub == 1) {
            q.x = pack2(pfa.x, pfa.y); q.y = pack2(pfb.x, pfb.y);
            q.z = pack2(pfc.x, pfc.y); q.w = 0x00003F80u;   // k14=1.0, k15=0
        }
        ((uint4*)U16)[(pl >> 4) * 112 + (pl & 15) * 7 + sub] = q;
    }

    // ---- s -> S rows (swizzled u32 writes); pads + 1.0 slot ----
    {
        unsigned int* srow = &S32[pl * 68];
        const int swzd = (pl & 7) << 2;
        s_chunk(A0, B0, C0, D0, sub, srow, swzd);
        if (sub < 2) s_chunk(A1, B1, C1, D1, 4 + sub, srow, swzd);
        if (sub == 2) {
            float s48 = fmaxf(bflo(tA) + bflo(tB), 0.f) + fmaxf(bflo(tC) + bflo(tD), 0.f);
            float s49 = fmaxf(bfhi(tA) + bfhi(tB), 0.f) + fmaxf(bfhi(tC) + bfhi(tD), 0.f);
            srow[24 ^ swzd] = pack2(s48, s49);
        }
        if (sub == 1) srow[25 ^ swzd] = 0x00003F80u;   // k50=1.0, k51=0
#pragma unroll
        for (int i = 0; i < 4; ++i) {
            int u = 51 + sub + 4 * i;
            if (u <= 63) srow[u ^ swzd] = 0u;
        }
    }

    // ---- PP & PA MFMA (A = W tiles, B = pf fragment; D[n][pair]) ----
    {
        const short8 bfrag = *(const short8*)(U16 + w * 896 + lr * 56 + lk * 8);
        const int row  = 16 * w + lr;          // this lane's pair row
        const int swzd = (row & 7) << 2;
        unsigned int* srow = &S32[row * 68];
        unsigned int* U32  = (unsigned int*)U16;

        // PP -> S k 52+n
#pragma unroll
        for (int nt = 0; nt < 4; ++nt) {
            short8 af = *(const short8*)(WPPb + (nt * 16 + lr) * 32 + lk * 8);
            float4v acc = __builtin_amdgcn_mfma_f32_16x16x32_bf16(
                af, bfrag, (float4v){0.f, 0.f, 0.f, 0.f}, 0, 0, 0);
            const int n0 = nt * 16 + lk * 4;
            if (n0 < 48) {
                uint2 v;
                v.x = pack2(fmaxf(acc[0], 0.f), fmaxf(acc[1], 0.f));
                v.y = pack2(fmaxf(acc[2], 0.f), fmaxf(acc[3], 0.f));
                *(uint2*)&srow[(26 + 8 * nt + 2 * lk) ^ swzd] = v;
            } else if (lk == 0) {
                srow[50 ^ swzd] = pack2(fmaxf(acc[0], 0.f), fmaxf(acc[1], 0.f));
            }
        }
        // PA -> U rows (overwrites pf region; bfrag already in regs)
#pragma unroll
        for (int nt = 0; nt < 4; ++nt) {
            short8 af = *(const short8*)(WPAb + (nt * 16 + lr) * 32 + lk * 8);
            float4v acc = __builtin_amdgcn_mfma_f32_16x16x32_bf16(
                af, bfrag, (float4v){0.f, 0.f, 0.f, 0.f}, 0, 0, 0);
            const int n0 = nt * 16 + lk * 4;
            const int ub = w * 448 + lr * 28;
            if (n0 < 48) {
                uint2 v;
                v.x = pack2(fmaxf(acc[0], 0.f), fmaxf(acc[1], 0.f));
                v.y = pack2(fmaxf(acc[2], 0.f), fmaxf(acc[3], 0.f));
                *(uint2*)&U32[ub + (n0 >> 1)] = v;
            } else if (lk == 0) {
                U32[ub + 24] = pack2(fmaxf(acc[0], 0.f), fmaxf(acc[1], 0.f));
            }
        }
    }

    // ---- P GEMM: A = WPb tiles, B = S fragments; D[n][pair] -> float2 stores ----
    {
        short8 sfrag[4];
#pragma unroll
        for (int ks = 0; ks < 4; ++ks) {
            const int inrow = (64 * ks + 16 * lk) ^ ((lr & 7) << 4);
            sfrag[ks] = *(const short8*)((const char*)&S32[(16 * w + lr) * 68] + inrow);
        }
        float* po = Pout + ((size_t)blk * 128 + 16 * w + lr) * 50;
#pragma unroll
        for (int nt = 0; nt < 4; ++nt) {
            float4v acc = {0.f, 0.f, 0.f, 0.f};
#pragma unroll
            for (int ks = 0; ks < 4; ++ks) {
                short8 wf = *(const short8*)(WPb + (nt * 16 + lr) * 128 + ks * 32 + lk * 8);
                acc = __builtin_amdgcn_mfma_f32_16x16x32_bf16(wf, sfrag[ks], acc, 0, 0, 0);
            }
            const int n0 = nt * 16 + lk * 4;
            if (n0 < 48) {
                float2 v0 = {fmaxf(acc[0], 0.f), fmaxf(acc[1], 0.f)};
                float2 v1 = {fmaxf(acc[2], 0.f), fmaxf(acc[3], 0.f)};
                *(float2*)(po + n0)     = v0;
                *(float2*)(po + n0 + 2) = v1;
            } else if (lk == 0) {
                float2 v0 = {fmaxf(acc[0], 0.f), fmaxf(acc[1], 0.f)};
                *(float2*)(po + 48) = v0;
            }
        }
    }

    // ---- segment-sum of PA ----
    __syncthreads();
    if (t < 128) {
        bool head = (t == 0) || (ps_lds[t] != ps_lds[t - 1]);
        if (head) {
            int idx = atomicAdd(&nheads, 1);
            head_list[idx] = (unsigned char)t;
        }
    }
    __syncthreads();

    const int nh = nheads;
    for (int iw = t; iw < nh * 50; iw += 512) {
        const int r0  = head_list[iw / 50];
        const int f   = iw % 50;
        const int seg = ps_lds[r0];
        float a0 = 0.0f;
        int rr = r0;
        do {
            a0 += bf2f(U16[(rr >> 4) * 896 + (rr & 15) * 56 + f]);
            ++rr;
        } while (rr < 128 && ps_lds[rr] == seg);
        atomicAdd(&PAsum[(size_t)seg * 50 + f], a0);
    }
}

// K3: A = relu(concat(AA, PAsum) @ W_A.T + b_A) (unchanged)
__global__ __launch_bounds__(256) __attribute__((amdgpu_waves_per_eu(2, 2)))
void k_atom_final(
    const float* __restrict__ AA, const float* __restrict__ PAsum,
    const float* __restrict__ W_A, const float* __restrict__ b_A,
    float* __restrict__ Aout)
{
    const int a = blockIdx.x * 256 + threadIdx.x;
    if (a >= NATOMS) return;
    const int o0 = blockIdx.y * 25;

    float v[100];
    {
        const float2* p1 = (const float2*)(AA + (size_t)a * 50);
        const float2* p2 = (const float2*)(PAsum + (size_t)a * 50);
#pragma unroll
        for (int q = 0; q < 25; ++q) {
            float2 u1 = p1[q], u2 = p2[q];
            v[2 * q] = u1.x;      v[2 * q + 1] = u1.y;
            v[50 + 2 * q] = u2.x; v[50 + 2 * q + 1] = u2.y;
        }
    }
    float* ao = Aout + (size_t)a * 50;
#pragma unroll 2
    for (int o = o0; o < o0 + 25; ++o) {
        const float4* w4 = (const float4*)(W_A + (size_t)o * 100);
        float acc = b_A[o];
#pragma unroll
        for (int q = 0; q < 25; ++q) {
            float4 w = w4[q];
            acc = fmaf(v[4 * q + 0], w.x, acc);
            acc = fmaf(v[4 * q + 1], w.y, acc);
            acc = fmaf(v[4 * q + 2], w.z, acc);
            acc = fmaf(v[4 * q + 3], w.w, acc);
        }
        ao[o] = fmaxf(acc, 0.0f);
    }
}

extern "C" void kernel_launch(void* const* d_in, const int* in_sizes, int n_in,
                              void* d_out, int out_size, void* d_ws, size_t ws_size,
                              hipStream_t stream)
{
    const float* atom_features = (const float*)d_in[0];
    const float* pair_features = (const float*)d_in[1];
    const int*   pair_split    = (const int*)d_in[2];
    const int*   atom_to_pair  = (const int*)d_in[3];
    const float* W_AA = (const float*)d_in[4];
    const float* b_AA = (const float*)d_in[5];
    const float* W_PA = (const float*)d_in[6];
    const float* b_PA = (const float*)d_in[7];
    const float* W_A  = (const float*)d_in[8];
    const float* b_A  = (const float*)d_in[9];
    const float* W_AP = (const float*)d_in[10];
    const float* b_AP = (const float*)d_in[11];
    const float* W_PP = (const float*)d_in[12];
    const float* b_PP = (const float*)d_in[13];
    const float* W_P  = (const float*)d_in[14];
    const float* b_P  = (const float*)d_in[15];

    float* out   = (float*)d_out;
    float* A_out = out;                              // [NATOMS,50]
    float* P_out = out + (size_t)NATOMS * 50;        // [NPAIRS,50]

    float*          AA    = (float*)d_ws;                               // 5,000,000 f32
    unsigned int*   XAu   = (unsigned int*)(AA + (size_t)NATOMS * 50);  // 5,600,000 u32
    float*          PAsum = (float*)(XAu + (size_t)NATOMS * 56);        // 5,000,000 f32
    unsigned short* WPb   = (unsigned short*)(PAsum + (size_t)NATOMS * 50);  // 8192 u16
    unsigned short* WPPb  = WPb + 64 * 128;                                  // 2048 u16
    unsigned short* WPAb  = WPPb + 64 * 32;                                  // 2048 u16

    hipMemsetAsync(PAsum, 0, (size_t)NATOMS * 50 * sizeof(float), stream);

    k_wconv<<<32, 256, 0, stream>>>(W_P, b_P, W_PP, b_PP, W_PA, b_PA, WPb, WPPb, WPAb);

    k_atom_pre<<<dim3(391, 2), 256, 0, stream>>>(
        atom_features, W_AA, b_AA, W_AP, b_AP, AA, XAu);

    k_pair<<<NPAIRS / 128, 512, 0, stream>>>(
        pair_features, pair_split, atom_to_pair,
        WPb, WPPb, WPAb, XAu, PAsum, P_out);

    k_atom_final<<<dim3(391, 2), 256, 0, stream>>>(
        AA, PAsum, W_A, b_A, A_out);
}